// Round 3
// baseline (750.001 us; speedup 1.0000x reference)
//
#include <hip/hip_runtime.h>
#include <hip/hip_bf16.h>
#include <stdint.h>

// Problem constants
#define TOK    8192      // B*S
#define DIN    4096
#define DOUT   4096
#define NEXP   8
#define RK     16
#define NRANK  128       // NEXP*RK
#define KE     4224      // DIN + NRANK (extended K)
#define SEQB   2048      // S (tokens per batch entry)
#define LSCALE 2.0f      // ALPHA/RANK
#define KSPLIT 4
#define KSLICE (DIN / KSPLIT)   // 1024

typedef __attribute__((ext_vector_type(8))) short bf8_t;   // 8 bf16 = 4 VGPRs
typedef __attribute__((ext_vector_type(4))) float f4_t;

__device__ __forceinline__ void async_copy16(const void* g, void* l) {
  __builtin_amdgcn_global_load_lds((const __attribute__((address_space(1))) void*)g,
                                   (__attribute__((address_space(3))) void*)l,
                                   16, 0, 0);
}

__device__ __forceinline__ ushort f2bf(float f) {
  __hip_bfloat16 h = __float2bfloat16(f);
  return *reinterpret_cast<ushort*>(&h);
}

// ---------- fused conversion kernel (fp32 -> bf16, memory-bound) ----------
#define R0 (TOK * DIN / 8)        // 4,194,304
#define R1 (DOUT * DIN / 8)       // 2,097,152
#define R2 (DOUT * NEXP * 2)      //    65,536
#define R3 (NRANK * DIN / 8)      //    65,536
#define RTOT (R0 + R1 + R2 + R3)  // 6,422,528  (= 25088 * 256)

__global__ __launch_bounds__(256)
void cvt_all_kernel(const float* __restrict__ x, const float* __restrict__ wb,
                    const float* __restrict__ lu, const float* __restrict__ ld,
                    ushort* __restrict__ Xe, ushort* __restrict__ Wc,
                    ushort* __restrict__ Ldb) {
  int i = blockIdx.x * 256 + threadIdx.x;
  const float* src;
  ushort* dst;
  if (i < R0) {
    int t = i >> 9;                    // DIN/8 = 512
    int c = (i & 511) * 8;
    src = x + (size_t)t * DIN + c;
    dst = Xe + (size_t)t * KE + c;
  } else if (i < R0 + R1) {
    int j = i - R0;
    int t = j >> 9;
    int c = (j & 511) * 8;
    src = wb + (size_t)t * DIN + c;
    dst = Wc + (size_t)t * KE + c;
  } else if (i < R0 + R1 + R2) {
    int j = i - (R0 + R1);
    int o = j >> 4;
    int rem = j & 15;
    int n = rem >> 1;
    int half = rem & 1;
    src = lu + ((size_t)n * DOUT + o) * RK + half * 8;
    dst = Wc + (size_t)o * KE + DIN + n * RK + half * 8;
  } else {
    int j = i - (R0 + R1 + R2);
    src = ld + (size_t)j * 8;
    dst = Ldb + (size_t)j * 8;
  }
  const float4* s = reinterpret_cast<const float4*>(src);
  float4 a = s[0], b = s[1];
  union { ushort u[8]; uint4 v; } o;
  o.u[0]=f2bf(a.x); o.u[1]=f2bf(a.y); o.u[2]=f2bf(a.z); o.u[3]=f2bf(a.w);
  o.u[4]=f2bf(b.x); o.u[5]=f2bf(b.y); o.u[6]=f2bf(b.z); o.u[7]=f2bf(b.w);
  *reinterpret_cast<uint4*>(dst) = o.v;
}

// ---------- down-projection GEMM: 128x128 tile, 64x64 wave tiles ----------
// D32[z] = Xe[:, z*KSLICE:(z+1)*KSLICE] @ Ldb^T, fp32 partials
__global__ __launch_bounds__(256)
void gemm_down(const ushort* __restrict__ A,
               const ushort* __restrict__ Bm,
               float* __restrict__ C) {
  __shared__ __align__(16) ushort As[128 * 32];
  __shared__ __align__(16) ushort Bs[128 * 32];

  const int tid  = threadIdx.x;
  const int wave = tid >> 6;
  const int lane = tid & 63;
  const int bm = blockIdx.y * 128;
  const int wm = wave & 1, wn = wave >> 1;

  f4_t acc[4][4];
#pragma unroll
  for (int i = 0; i < 4; i++)
#pragma unroll
    for (int j = 0; j < 4; j++) acc[i][j] = (f4_t){0.f, 0.f, 0.f, 0.f};

  const int f0 = tid * 8;
  const int r0 = f0 >> 5, c0 = f0 & 31;
  const int f1 = (256 + tid) * 8;
  const int r1 = f1 >> 5, c1 = f1 & 31;
  const int l0 = (wave << 6) * 8;
  const int l1 = (256 + (wave << 6)) * 8;

  const ushort* Ar = As + (wm * 64 + (lane & 15)) * 32 + (lane >> 4) * 8;
  const ushort* Br = Bs + (wn * 64 + (lane & 15)) * 32 + (lane >> 4) * 8;

  const int kbase = blockIdx.z * KSLICE;
  const int kend  = kbase + KSLICE;

  for (int k0 = kbase; k0 < kend; k0 += 32) {
    __syncthreads();
    async_copy16(A  + (size_t)(bm + r0) * KE  + k0 + c0, (void*)(As + l0));
    async_copy16(A  + (size_t)(bm + r1) * KE  + k0 + c1, (void*)(As + l1));
    async_copy16(Bm + (size_t)r0 * DIN + k0 + c0, (void*)(Bs + l0));
    async_copy16(Bm + (size_t)r1 * DIN + k0 + c1, (void*)(Bs + l1));
    __syncthreads();
    bf8_t av[4], bv[4];
#pragma unroll
    for (int i = 0; i < 4; i++) av[i] = *(const bf8_t*)(Ar + i * 16 * 32);
#pragma unroll
    for (int j = 0; j < 4; j++) bv[j] = *(const bf8_t*)(Br + j * 16 * 32);
#pragma unroll
    for (int i = 0; i < 4; i++)
#pragma unroll
      for (int j = 0; j < 4; j++)
        acc[i][j] = __builtin_amdgcn_mfma_f32_16x16x32_bf16(av[i], bv[j], acc[i][j], 0, 0, 0);
  }

  float* Dz = C + (size_t)blockIdx.z * TOK * NRANK;
#pragma unroll
  for (int i = 0; i < 4; i++) {
    int row = bm + wm * 64 + i * 16 + (lane >> 4) * 4;
#pragma unroll
    for (int j = 0; j < 4; j++) {
      int col = wn * 64 + j * 16 + (lane & 15);
#pragma unroll
      for (int rr = 0; rr < 4; rr++)
        Dz[(size_t)(row + rr) * NRANK + col] = acc[i][j][rr];
    }
  }
}

// ---------- main GEMM: 256x256 block tile, 4 waves x 128x128 wave tile ----------
// out[TOK,DOUT] = Xe[TOK,KE] @ Wc[DOUT,KE]^T
// Double-buffered LDS (64 KB), 1 barrier/k-step, prefetch next step after barrier.
// LDS:MFMA per block-step = 500:1030 cyc -> MFMA-bound (vs 256:258 for 64x64 tiles).
#define NK (KE / 32)   // 132

__global__ __launch_bounds__(256, 1)
void gemm_main(const ushort* __restrict__ A,
               const ushort* __restrict__ Bm,
               float* __restrict__ C) {
  __shared__ __align__(16) ushort As[2][256 * 32];   // 16 KB per buffer
  __shared__ __align__(16) ushort Bs[2][256 * 32];   // total 64 KB

  const int tid  = threadIdx.x;
  const int wave = tid >> 6;
  const int lane = tid & 63;

  // XCD-aware swizzle: each XCD owns 2 n-tiles, sweeps m-tiles
  const int bid = blockIdx.x;            // 0..511
  const int xcd = bid & 7;
  const int idx = bid >> 3;              // 0..63
  const int nt  = xcd * 2 + (idx & 1);   // 0..15
  const int mt  = idx >> 1;              // 0..31
  const int bm = mt * 256;
  const int bn = nt * 256;
  const int wm = wave & 1, wn = wave >> 1;

  f4_t acc[8][8];
#pragma unroll
  for (int i = 0; i < 8; i++)
#pragma unroll
    for (int j = 0; j < 8; j++) acc[i][j] = (f4_t){0.f, 0.f, 0.f, 0.f};

  // staging: wave w stages A rows [w*64, (w+1)*64) and B rows likewise,
  // 4 instrs each; lane -> row +(lane>>2), 16B chunk (lane&3)
  const int srow   = wave * 64 + (lane >> 2);
  const int schunk = (lane & 3) * 8;               // element offset
  const ushort* gA = A  + (size_t)(bm + srow) * KE + schunk;
  const ushort* gB = Bm + (size_t)(bn + srow) * KE + schunk;
  const int lbase = wave * 64 * 32;                // wave-uniform LDS element base

  // fragment read pointers (element offsets within a buffer)
  const int aoff = (wm * 128 + (lane & 15)) * 32 + (lane >> 4) * 8;
  const int boff = (wn * 128 + (lane & 15)) * 32 + (lane >> 4) * 8;

  // prologue: stage step 0 into buf 0
  {
    const ushort* a = gA;
    const ushort* b = gB;
#pragma unroll
    for (int j2 = 0; j2 < 4; j2++) {
      async_copy16(a + (size_t)j2 * 16 * KE, (void*)(&As[0][lbase + j2 * 16 * 32]));
      async_copy16(b + (size_t)j2 * 16 * KE, (void*)(&Bs[0][lbase + j2 * 16 * 32]));
    }
  }

  for (int k = 0; k < NK; k++) {
    const int buf = k & 1;
    __syncthreads();   // drains vmcnt: step-k stage complete; prev readers done
    if (k + 1 < NK) {
      const int nbuf = (k + 1) & 1;
      const ushort* a = gA + (size_t)(k + 1) * 32;
      const ushort* b = gB + (size_t)(k + 1) * 32;
#pragma unroll
      for (int j2 = 0; j2 < 4; j2++) {
        async_copy16(a + (size_t)j2 * 16 * KE, (void*)(&As[nbuf][lbase + j2 * 16 * 32]));
        async_copy16(b + (size_t)j2 * 16 * KE, (void*)(&Bs[nbuf][lbase + j2 * 16 * 32]));
      }
    }
    const ushort* Ar = &As[buf][aoff];
    const ushort* Br = &Bs[buf][boff];
    bf8_t bv[8];
#pragma unroll
    for (int jn = 0; jn < 8; jn++) bv[jn] = *(const bf8_t*)(Br + jn * 16 * 32);
#pragma unroll
    for (int i = 0; i < 8; i++) {
      bf8_t av = *(const bf8_t*)(Ar + i * 16 * 32);
#pragma unroll
      for (int jn = 0; jn < 8; jn++)
        acc[i][jn] = __builtin_amdgcn_mfma_f32_16x16x32_bf16(av, bv[jn], acc[i][jn], 0, 0, 0);
    }
  }

  // epilogue: C/D layout col=lane&15, row=(lane>>4)*4+rr per 16x16 frag
#pragma unroll
  for (int i = 0; i < 8; i++) {
    int row = bm + wm * 128 + i * 16 + (lane >> 4) * 4;
#pragma unroll
    for (int jn = 0; jn < 8; jn++) {
      int col = bn + wn * 128 + jn * 16 + (lane & 15);
#pragma unroll
      for (int rr = 0; rr < 4; rr++)
        C[(size_t)(row + rr) * DOUT + col] = acc[i][jn][rr];
    }
  }
}

// reduce split-K slices, scale by routing*LSCALE, pack bf16 into Xe extension cols
__global__ void scale_store_kernel(const float* __restrict__ D32,
                                   const float* __restrict__ rw,
                                   ushort* __restrict__ Xe) {
  int i = blockIdx.x * 256 + threadIdx.x;          // [0, TOK*NRANK/4)
  int t = i >> 5;                                  // token
  int g = (i & 31) * 4;                            // col base (4 cols, same expert)
  size_t base = (size_t)t * NRANK + g;
  const size_t ss = (size_t)TOK * NRANK;
  float4 a = *reinterpret_cast<const float4*>(D32 + base);
  float4 b = *reinterpret_cast<const float4*>(D32 + ss + base);
  float4 c = *reinterpret_cast<const float4*>(D32 + 2 * ss + base);
  float4 d = *reinterpret_cast<const float4*>(D32 + 3 * ss + base);
  int n = g >> 4;                                  // expert index
  int bb = t / SEQB;
  float s = rw[bb * NEXP + n] * LSCALE;
  union { ushort u[4]; uint2 v; } o;
  o.u[0] = f2bf((a.x + b.x + c.x + d.x) * s);
  o.u[1] = f2bf((a.y + b.y + c.y + d.y) * s);
  o.u[2] = f2bf((a.z + b.z + c.z + d.z) * s);
  o.u[3] = f2bf((a.w + b.w + c.w + d.w) * s);
  *reinterpret_cast<uint2*>(Xe + (size_t)t * KE + DIN + g) = o.v;
}

extern "C" void kernel_launch(void* const* d_in, const int* in_sizes, int n_in,
                              void* d_out, int out_size, void* d_ws, size_t ws_size,
                              hipStream_t stream) {
  const float* x  = (const float*)d_in[0];
  const float* rw = (const float*)d_in[1];
  const float* wb = (const float*)d_in[2];
  const float* ld = (const float*)d_in[3];
  const float* lu = (const float*)d_in[4];
  float* out = (float*)d_out;

  // workspace layout (bf16 elements unless noted)
  ushort* Xe  = (ushort*)d_ws;                         // TOK*KE el
  ushort* Wc  = Xe + (size_t)TOK * KE;                 // DOUT*KE el
  ushort* Ldb = Wc + (size_t)DOUT * KE;                // NRANK*DIN el
  float*  D32 = (float*)(Ldb + (size_t)NRANK * DIN);   // KSPLIT*TOK*NRANK fp32

  // fused conversion (x, W_base, lora_up, lora_down -> bf16)
  cvt_all_kernel<<<RTOT / 256, 256, 0, stream>>>(x, wb, lu, ld, Xe, Wc, Ldb);

  // down-projection split-K
  gemm_down<<<dim3(1, TOK / 128, KSPLIT), 256, 0, stream>>>(Xe, Ldb, D32);
  // reduce + routing scale + pack into Xe extension columns
  scale_store_kernel<<<TOK * NRANK / 4 / 256, 256, 0, stream>>>(D32, rw, Xe);
  // main GEMM: 256x256 tiles, 128x128 wave tiles, double-buffered LDS
  gemm_main<<<dim3((TOK / 256) * (DOUT / 256)), 256, 0, stream>>>(Xe, Wc, out);
}